// Round 14
// baseline (329.735 us; speedup 1.0000x reference)
//
#include <hip/hip_runtime.h>
#include <hip/hip_bf16.h>

typedef unsigned short u16;
typedef __bf16 bf16x8 __attribute__((ext_vector_type(8)));
typedef u16 u16x4 __attribute__((ext_vector_type(4)));
typedef u16 u16x8 __attribute__((ext_vector_type(8)));
typedef float f32x4 __attribute__((ext_vector_type(4)));

#define S_LEN  2048
#define HID    4096
#define NHEADS 32
#define NKV    8
#define HD     128
#define QDIM   (NHEADS*HD)   // 4096
#define KVDIM  (NKV*HD)      // 1024
#define NT     (S_LEN/64)    // 32 kv/q tiles

__device__ __forceinline__ u16 f2bf(float f) {
  unsigned u = __float_as_uint(f);
  u += 0x7fff + ((u >> 16) & 1);   // RNE
  return (u16)(u >> 16);
}
__device__ __forceinline__ void lds_load16(const u16* g, u16* l) {
  __builtin_amdgcn_global_load_lds(
      (__attribute__((address_space(1))) void*)(g),
      (__attribute__((address_space(3))) void*)(l), 16, 0, 0);
}

// ---------------------------------------------------------------------------
// Segmented fp32 -> bf16 bulk convert: 4 buffers in one launch. n = elems/8.
// ---------------------------------------------------------------------------
__global__ __launch_bounds__(256) void f2b4(
    const float* __restrict__ s0, u16* __restrict__ d0, long n0,
    const float* __restrict__ s1, u16* __restrict__ d1, long n1,
    const float* __restrict__ s2, u16* __restrict__ d2, long n2,
    const float* __restrict__ s3, u16* __restrict__ d3, long n3)
{
  const float* s; u16* d; long n; int b0, nb;
  const int b = blockIdx.x;
  if (b < 1024)      { s=s0; d=d0; n=n0; b0=0;    nb=1024; }
  else if (b < 3072) { s=s1; d=d1; n=n1; b0=1024; nb=2048; }
  else if (b < 3584) { s=s2; d=d2; n=n2; b0=3072; nb=512;  }
  else               { s=s3; d=d3; n=n3; b0=3584; nb=512;  }
  long i = (long)(b - b0)*256 + threadIdx.x;
  const long stride = (long)nb*256;
  for (; i < n; i += stride) {
    f32x4 a = ((const f32x4*)s)[i*2];
    f32x4 c = ((const f32x4*)s)[i*2 + 1];
    u16x8 o;
    #pragma unroll
    for (int j = 0; j < 4; ++j) { o[j] = f2bf(a[j]); o[4+j] = f2bf(c[j]); }
    ((u16x8*)d)[i] = o;
  }
}

// standalone Wo convert (BW-bound dispatch streams at ~6 TB/s; fusing it
// into latency-bound attn cost +18us in r13 — keep it separate).
__global__ __launch_bounds__(256) void f2b(
    const float* __restrict__ in, u16* __restrict__ out, long n8)
{
  long i = (long)blockIdx.x * blockDim.x + threadIdx.x;
  const long stride = (long)gridDim.x * blockDim.x;
  for (; i < n8; i += stride) {
    f32x4 a = ((const f32x4*)in)[i*2];
    f32x4 b = ((const f32x4*)in)[i*2 + 1];
    u16x8 o;
    #pragma unroll
    for (int j = 0; j < 4; ++j) { o[j] = f2bf(a[j]); o[4+j] = f2bf(b[j]); }
    ((u16x8*)out)[i] = o;
  }
}

// ---------------------------------------------------------------------------
// QKV projection GEMM: 128x192 tile, grid 32x16 = 512 blocks = 2/CU
// (verified rounds 12-13: ~102 us, cross-block stall overlap).
// ---------------------------------------------------------------------------
template<int K>
__global__ __launch_bounds__(512, 4) void gemmQ(
    const u16* __restrict__ A, const u16* __restrict__ B,
    u16* __restrict__ Cq, u16* __restrict__ Ck, u16* __restrict__ Cv)
{
  __shared__ u16 lds[40960];   // A: [0,16384) 2x8192; B: [16384,40960) 2x12288
  const int tid  = threadIdx.x;
  const int lane = tid & 63;
  const int w    = tid >> 6;
  const int wr   = w >> 2, wc = w & 3;
  const int l16  = lane & 15, lhi = lane >> 4;
  const long arow0 = (long)blockIdx.y * 128;
  const long brow0 = (long)blockIdx.x * 192;
  const int ntiles = K >> 6;

  const int cu = ((lane & 7) ^ (lane >> 3)) * 8;
  const int wl = w*8 + (lane >> 3);            // [0,64)
  const u16* Ag[2];
  #pragma unroll
  for (int r = 0; r < 2; ++r)
    Ag[r] = A + (arow0 + r*64 + wl)*(long)K + cu;
  const u16* Bg[3];
  #pragma unroll
  for (int r = 0; r < 2; ++r) {
    const int rp = r*64 + wl;
    Bg[r] = B + (brow0 + (rp >> 5)*48 + (rp & 31))*(long)K + cu;
  }
  Bg[2] = B + (brow0 + (wl >> 4)*48 + 32 + (wl & 15))*(long)K + cu;

  auto stageA = [&](int kt) {                  // whole A tile: rounds 0,1
    u16* d = lds + ((kt & 1) << 13) + w*512;
    lds_load16(Ag[0] + (long)kt*64, d);
    lds_load16(Ag[1] + (long)kt*64, d + 4096);
  };
  auto stageB0 = [&](int kt) {                 // B part0: rounds 0,1
    u16* d = lds + 16384 + (kt & 1)*12288 + w*512;
    lds_load16(Bg[0] + (long)kt*64, d);
    lds_load16(Bg[1] + (long)kt*64, d + 4096);
  };
  auto stageB1 = [&](int kt) {                 // B part1: round 2
    u16* d = lds + 16384 + (kt & 1)*12288 + w*512;
    lds_load16(Bg[2] + (long)kt*64, d + 8192);
  };

  const int xr = (l16 & 7) << 3;
  int offA[2][2], offB[2][2], offB2[2];
  #pragma unroll
  for (int m2 = 0; m2 < 2; ++m2)
    #pragma unroll
    for (int ks = 0; ks < 2; ++ks)
      offA[m2][ks] = (wr*64 + m2*16 + l16)*64 + ((ks*32 + lhi*8) ^ xr);
  #pragma unroll
  for (int n2 = 0; n2 < 2; ++n2)
    #pragma unroll
    for (int ks = 0; ks < 2; ++ks)
      offB[n2][ks] = (wc*32 + n2*16 + l16)*64 + ((ks*32 + lhi*8) ^ xr);
  #pragma unroll
  for (int ks = 0; ks < 2; ++ks)
    offB2[ks] = 8192 + (wc*16 + l16)*64 + ((ks*32 + lhi*8) ^ xr);

  f32x4 acc[4][3] = {};

  stageA(0); stageB0(0); stageB1(0);
  stageB0(1); stageB1(1);
  asm volatile("s_waitcnt vmcnt(3)" ::: "memory");
  __builtin_amdgcn_s_barrier();

  #pragma unroll 2
  for (int t = 0; t < ntiles; ++t) {
    const int Ab = (t & 1) << 13;
    const int Bb = 16384 + (t & 1)*12288;
    bf16x8 af[2][2], af2[2][2], bf[2][2], bf2[2];

    // ---------- phase 1: A half0 x B part0 -> acc[0:2][0:2] ----------
    #pragma unroll
    for (int m2 = 0; m2 < 2; ++m2)
      #pragma unroll
      for (int ks = 0; ks < 2; ++ks)
        af[m2][ks] = *(const bf16x8*)(lds + Ab + offA[m2][ks]);
    #pragma unroll
    for (int n2 = 0; n2 < 2; ++n2)
      #pragma unroll
      for (int ks = 0; ks < 2; ++ks)
        bf[n2][ks] = *(const bf16x8*)(lds + Bb + offB[n2][ks]);
    if (t + 1 < ntiles) stageA(t + 1);
    __builtin_amdgcn_s_barrier();
    asm volatile("s_waitcnt lgkmcnt(0)" ::: "memory");
    __builtin_amdgcn_s_setprio(1);
    #pragma unroll
    for (int m2 = 0; m2 < 2; ++m2)
      #pragma unroll
      for (int n2 = 0; n2 < 2; ++n2)
        #pragma unroll
        for (int ks = 0; ks < 2; ++ks)
          acc[m2][n2] = __builtin_amdgcn_mfma_f32_16x16x32_bf16(
              af[m2][ks], bf[n2][ks], acc[m2][n2], 0, 0, 0);
    __builtin_amdgcn_s_setprio(0);
    __builtin_amdgcn_s_barrier();

    // ---------- phase 2: A half0 x B part1 -> acc[0:2][2] ----------
    #pragma unroll
    for (int ks = 0; ks < 2; ++ks)
      bf2[ks] = *(const bf16x8*)(lds + Bb + offB2[ks]);
    if (t + 2 < ntiles) stageB0(t + 2);
    __builtin_amdgcn_s_barrier();
    asm volatile("s_waitcnt lgkmcnt(0)" ::: "memory");
    __builtin_amdgcn_s_setprio(1);
    #pragma unroll
    for (int m2 = 0; m2 < 2; ++m2)
      #pragma unroll
      for (int ks = 0; ks < 2; ++ks)
        acc[m2][2] = __builtin_amdgcn_mfma_f32_16x16x32_bf16(
            af[m2][ks], bf2[ks], acc[m2][2], 0, 0, 0);
    __builtin_amdgcn_s_setprio(0);
    __builtin_amdgcn_s_barrier();

    // ---------- phase 3: A half1 x B part1 -> acc[2:4][2] ----------
    #pragma unroll
    for (int m2 = 0; m2 < 2; ++m2)
      #pragma unroll
      for (int ks = 0; ks < 2; ++ks)
        af2[m2][ks] = *(const bf16x8*)(lds + Ab + 2048 + offA[m2][ks]);
    if (t + 2 < ntiles) stageB1(t + 2);
    __builtin_amdgcn_s_barrier();
    asm volatile("s_waitcnt lgkmcnt(0)" ::: "memory");
    __builtin_amdgcn_s_setprio(1);
    #pragma unroll
    for (int m2 = 0; m2 < 2; ++m2)
      #pragma unroll
      for (int ks = 0; ks < 2; ++ks)
        acc[2+m2][2] = __builtin_amdgcn_mfma_f32_16x16x32_bf16(
            af2[m2][ks], bf2[ks], acc[2+m2][2], 0, 0, 0);
    __builtin_amdgcn_s_setprio(0);
    __builtin_amdgcn_s_barrier();

    // ---------- phase 4: A half1 x B part0 -> acc[2:4][0:2] ----------
    __builtin_amdgcn_s_setprio(1);
    #pragma unroll
    for (int m2 = 0; m2 < 2; ++m2)
      #pragma unroll
      for (int n2 = 0; n2 < 2; ++n2)
        #pragma unroll
        for (int ks = 0; ks < 2; ++ks)
          acc[2+m2][n2] = __builtin_amdgcn_mfma_f32_16x16x32_bf16(
              af2[m2][ks], bf[n2][ks], acc[2+m2][n2], 0, 0, 0);
    __builtin_amdgcn_s_setprio(0);
    if (t + 2 < ntiles) { asm volatile("s_waitcnt vmcnt(3)" ::: "memory"); }
    else                { asm volatile("s_waitcnt vmcnt(0)" ::: "memory"); }
    __builtin_amdgcn_s_barrier();
  }

  // epilogue: C/D layout col = lane&15, row = (lane>>4)*4 + reg
  #pragma unroll
  for (int m = 0; m < 4; ++m) {
    const long row = arow0 + wr*64 + m*16 + lhi*4;
    #pragma unroll
    for (int n = 0; n < 3; ++n) {
      const long col = brow0 + wc*48 + n*16 + l16;
      if (col < QDIM) {
        #pragma unroll
        for (int r = 0; r < 4; ++r)
          Cq[(row + r)*QDIM + col] = f2bf(acc[m][n][r]);
      } else if (col < QDIM + KVDIM) {
        #pragma unroll
        for (int r = 0; r < 4; ++r)
          Ck[(row + r)*KVDIM + (col - QDIM)] = f2bf(acc[m][n][r]);
      } else {
        u16x4 o;
        #pragma unroll
        for (int r = 0; r < 4; ++r) o[r] = f2bf(acc[m][n][r]);
        *(u16x4*)(Cv + (col - QDIM - KVDIM)*(long)S_LEN + row) = o;
      }
    }
  }
}

// ---------------------------------------------------------------------------
// Final projection GEMM: 128x128 tile, grid 32x16 = 512 blocks = 2/CU
// (verified round 13: ~66 us). 8 waves 2Mx4N, per-wave 64x32, acc[4][2].
// ---------------------------------------------------------------------------
template<int N, int K>
__global__ __launch_bounds__(512, 4) void gemmF(
    const u16* __restrict__ A, const u16* __restrict__ B,
    float* __restrict__ C)
{
  __shared__ u16 lds[32768];   // A: [0,16384) 2x8192; B: [16384,32768) 2x8192
  const int tid  = threadIdx.x;
  const int lane = tid & 63;
  const int w    = tid >> 6;
  const int wr   = w >> 2, wc = w & 3;
  const int l16  = lane & 15, lhi = lane >> 4;
  const long arow0 = (long)blockIdx.y * 128;
  const long brow0 = (long)blockIdx.x * 128;
  const int ntiles = K >> 6;

  const int cu = ((lane & 7) ^ (lane >> 3)) * 8;
  const int wl = w*8 + (lane >> 3);            // [0,64)
  const u16* Ag[2];
  #pragma unroll
  for (int r = 0; r < 2; ++r)
    Ag[r] = A + (arow0 + r*64 + wl)*(long)K + cu;
  const u16* Bg0 = B + (brow0 + (wl >> 4)*32      + (wl & 15))*(long)K + cu;
  const u16* Bg1 = B + (brow0 + (wl >> 4)*32 + 16 + (wl & 15))*(long)K + cu;

  auto stageA = [&](int kt) {                  // whole A tile: 2 rounds
    u16* d = lds + ((kt & 1) << 13) + w*512;
    lds_load16(Ag[0] + (long)kt*64, d);
    lds_load16(Ag[1] + (long)kt*64, d + 4096);
  };
  auto stageB0 = [&](int kt) {                 // B part0: 1 round
    lds_load16(Bg0 + (long)kt*64, lds + 16384 + ((kt & 1) << 13) + w*512);
  };
  auto stageB1 = [&](int kt) {                 // B part1: 1 round
    lds_load16(Bg1 + (long)kt*64, lds + 16384 + ((kt & 1) << 13) + 4096 + w*512);
  };

  const int xr = (l16 & 7) << 3;
  int offA[2][2], offB[2], offB2[2];
  #pragma unroll
  for (int m2 = 0; m2 < 2; ++m2)
    #pragma unroll
    for (int ks = 0; ks < 2; ++ks)
      offA[m2][ks] = (wr*64 + m2*16 + l16)*64 + ((ks*32 + lhi*8) ^ xr);
  #pragma unroll
  for (int ks = 0; ks < 2; ++ks) {
    offB[ks]  = (wc*16 + l16)*64 + ((ks*32 + lhi*8) ^ xr);
    offB2[ks] = 4096 + offB[ks];
  }

  f32x4 acc[4][2] = {};

  // prologue: tile0 fully (4 loads), tile1's B (2 loads)
  stageA(0); stageB0(0); stageB1(0);
  stageB0(1); stageB1(1);
  asm volatile("s_waitcnt vmcnt(2)" ::: "memory");
  __builtin_amdgcn_s_barrier();

  #pragma unroll 2
  for (int t = 0; t < ntiles; ++t) {
    const int Ab = (t & 1) << 13;
    const int Bb = 16384 + ((t & 1) << 13);
    bf16x8 af[2][2], af2[2][2], bf[2], bf2[2];

    // ---------- phase 1: A half0 x B part0 -> acc[0:2][0] ----------
    #pragma unroll
    for (int m2 = 0; m2 < 2; ++m2)
      #pragma unroll
      for (int ks = 0; ks < 2; ++ks)
        af[m2][ks] = *(const bf16x8*)(lds + Ab + offA[m2][ks]);
    #pragma unroll
    for (int ks = 0; ks < 2; ++ks)
      bf[ks] = *(const bf16x8*)(lds + Bb + offB[ks]);
    if (t + 1 < ntiles) stageA(t + 1);
    __builtin_amdgcn_s_barrier();
    asm volatile("s_waitcnt lgkmcnt(0)" ::: "memory");
    __builtin_amdgcn_s_setprio(1);
    #pragma unroll
    for (int m2 = 0; m2 < 2; ++m2)
      #pragma unroll
      for (int ks = 0; ks < 2; ++ks)
        acc[m2][0] = __builtin_amdgcn_mfma_f32_16x16x32_bf16(
            af[m2][ks], bf[ks], acc[m2][0], 0, 0, 0);
    __builtin_amdgcn_s_setprio(0);
    __builtin_amdgcn_s_barrier();

    // ---------- phase 2: A half0 x B part1 -> acc[0:2][1] ----------
    #pragma unroll
    for (int ks = 0; ks < 2; ++ks)
      bf2[ks] = *(const bf16x8*)(lds + Bb + offB2[ks]);
    if (t + 2 < ntiles) stageB0(t + 2);
    __builtin_amdgcn_s_barrier();
    asm volatile("s_waitcnt lgkmcnt(0)" ::: "memory");
    __builtin_amdgcn_s_setprio(1);
    #pragma unroll
    for (int m2 = 0; m2 < 2; ++m2)
      #pragma unroll
      for (int ks = 0; ks < 2; ++ks)
        acc[m2][1] = __builtin_amdgcn_mfma_f32_16x16x32_bf16(
            af[m2][ks], bf2[ks], acc[m2][1], 0, 0, 0);
    __builtin_amdgcn_s_setprio(0);
    __builtin_amdgcn_s_barrier();

    // ---------- phase 3: A half1 x B part1 -> acc[2:4][1] ----------
    #pragma unroll
    for (int m2 = 0; m2 < 2; ++m2)
      #pragma unroll
      for (int ks = 0; ks < 2; ++ks)
        af2[m2][ks] = *(const bf16x8*)(lds + Ab + 2048 + offA[m2][ks]);
    if (t + 2 < ntiles) stageB1(t + 2);
    __builtin_amdgcn_s_barrier();
    asm volatile("s_waitcnt lgkmcnt(0)" ::: "memory");
    __builtin_amdgcn_s_setprio(1);
    #pragma unroll
    for (int m2 = 0; m2 < 2; ++m2)
      #pragma unroll
      for (int ks = 0; ks < 2; ++ks)
        acc[2+m2][1] = __builtin_amdgcn_mfma_f32_16x16x32_bf16(
            af2[m2][ks], bf2[ks], acc[2+m2][1], 0, 0, 0);
    __builtin_amdgcn_s_setprio(0);
    __builtin_amdgcn_s_barrier();

    // ---------- phase 4: A half1 x B part0 -> acc[2:4][0] ----------
    __builtin_amdgcn_s_setprio(1);
    #pragma unroll
    for (int m2 = 0; m2 < 2; ++m2)
      #pragma unroll
      for (int ks = 0; ks < 2; ++ks)
        acc[2+m2][0] = __builtin_amdgcn_mfma_f32_16x16x32_bf16(
            af2[m2][ks], bf[ks], acc[2+m2][0], 0, 0, 0);
    __builtin_amdgcn_s_setprio(0);
    if (t + 2 < ntiles) { asm volatile("s_waitcnt vmcnt(2)" ::: "memory"); }
    else                { asm volatile("s_waitcnt vmcnt(0)" ::: "memory"); }
    __builtin_amdgcn_s_barrier();
  }

  // epilogue: row = arow0 + wr*64 + m*16 + lhi*4, col = brow0 + wc*32 + n*16 + l16
  #pragma unroll
  for (int m = 0; m < 4; ++m) {
    const long row = arow0 + wr*64 + m*16 + lhi*4;
    #pragma unroll
    for (int n = 0; n < 2; ++n) {
      const long col = brow0 + wc*32 + n*16 + l16;
      #pragma unroll
      for (int r = 0; r < 4; ++r)
        C[(row + r)*N + col] = acc[m][n][r];
    }
  }
}

// ---------------------------------------------------------------------------
// Fused per-head RMSNorm + RoPE for BOTH Q and K in one launch, in place.
// ---------------------------------------------------------------------------
__global__ __launch_bounds__(256) void norm_rope2(
    u16* __restrict__ Qb, u16* __restrict__ Kb,
    const float* __restrict__ qw, const float* __restrict__ kw,
    const int* __restrict__ pos)
{
  const int row  = blockIdx.x * 4 + (threadIdx.x >> 6);
  const int lane = threadIdx.x & 63;
  u16* p; const float* nw; float sc; int s;
  if (row < S_LEN*NHEADS) {
    p = Qb + (long)row * HD; nw = qw; sc = 0.08838834764831845f; s = row >> 5;
  } else {
    const int r2 = row - S_LEN*NHEADS;
    p = Kb + (long)r2 * HD; nw = kw; sc = 1.0f; s = r2 >> 3;
  }

  float x1 = __uint_as_float(((unsigned)p[lane]) << 16);
  float x2 = __uint_as_float(((unsigned)p[lane + 64]) << 16);
  float ss = x1*x1 + x2*x2;
  #pragma unroll
  for (int m = 32; m >= 1; m >>= 1) ss += __shfl_xor(ss, m);
  const float inv = rsqrtf(ss * (1.0f/128.0f) + 1e-6f);
  x1 *= inv * nw[lane];
  x2 *= inv * nw[lane + 64];

  const float inv_freq = expf(-(float)lane * (13.815510557964274f / 64.0f));
  const float ang = (float)pos[s] * inv_freq;
  float sn, cs;
  sincosf(ang, &sn, &cs);
  p[lane]      = f2bf((x1*cs - x2*sn) * sc);
  p[lane + 64] = f2bf((x2*cs + x1*sn) * sc);
}

// ---------------------------------------------------------------------------
// Causal flash attention — EXACT round-7/12 kernel (measured 120.3 us).
// XCD chunk (FETCH 15.4MB) + balanced per-CU T assignment; DMA staging,
// 2 __syncthreads/tile, 40KB LDS, 4 blocks/CU, 16 waves/CU.
// ---------------------------------------------------------------------------
__global__ __launch_bounds__(256, 4) void attn(
    const u16* __restrict__ Q, const u16* __restrict__ K,
    const u16* __restrict__ VT, u16* __restrict__ O)
{
  __shared__ u16 Ks[64*128];   // [kv][d], XOR-swizzled cols
  __shared__ u16 Vt[128*64];   // [d][kv], XOR-swizzled cols
  __shared__ u16 Ps[4*16*64];  // per-wave P tile

  const int tid  = threadIdx.x;
  const int lane = tid & 63;
  const int w    = tid >> 6;
  const int l16  = lane & 15, lhi = lane >> 4;

  const int x8  = blockIdx.x & 7;        // XCD = kv-head group
  const int idx = blockIdx.x >> 3;       // [0,128) within chunk
  const int cc  = idx & 31;              // CU within XCD
  const int jj  = idx >> 5;              // head within group
  const int h   = x8*4 + jj;
  const int kh  = x8;                    // GQA 4:1
  const int T   = (jj & 1) ? cc : (NT - 1) - cc;
  const int qrow0 = T*64 + w*16;

  bf16x8 qf[4];
  #pragma unroll
  for (int ks = 0; ks < 4; ++ks)
    qf[ks] = *(const bf16x8*)(Q + (long)(qrow0 + l16)*QDIM + h*HD + ks*32 + lhi*8);

  float mr[4] = {-1e30f,-1e30f,-1e30f,-1e30f};
  float lr[4] = {0.f,0.f,0.f,0.f};
  f32x4 of[8] = {};
  u16* Pw = Ps + w*16*64;

  for (int t = 0; t <= T; ++t) {
    const int kv0 = t * 64;
    // stage K tile [64][128]
    #pragma unroll
    for (int i = 0; i < 4; ++i) {
      const int r   = w*16 + i*4 + lhi;
      const int col = (l16*8) ^ ((r & 7) << 3);
      lds_load16(K + (long)(kv0 + r)*KVDIM + kh*HD + col,
                 Ks + (w*16 + i*4)*128);
    }
    // stage V^T tile [128][64]
    #pragma unroll
    for (int i = 0; i < 4; ++i) {
      const int r   = w*32 + i*8 + (lane >> 3);
      const int col = ((lane & 7)*8) ^ ((r & 7) << 3);
      lds_load16(VT + (long)(kh*HD + r)*S_LEN + kv0 + col,
                 Vt + (w*32 + i*8)*64);
    }
    __syncthreads();

    // ---- QK^T ----
    f32x4 sa[4] = {};
    __builtin_amdgcn_s_setprio(1);
    #pragma unroll
    for (int n = 0; n < 4; ++n)
      #pragma unroll
      for (int ks = 0; ks < 4; ++ks) {
        bf16x8 kf = *(const bf16x8*)(
            Ks + (n*16 + l16)*128 + ((ks*32 + lhi*8) ^ ((l16 & 7) << 3)));
        sa[n] = __builtin_amdgcn_mfma_f32_16x16x32_bf16(qf[ks], kf, sa[n], 0, 0, 0);
      }
    __builtin_amdgcn_s_setprio(0);

    // ---- online softmax, defer-max (THR=8) ----
    const bool diag = (t == T);
    float pm[4];
    #pragma unroll
    for (int r = 0; r < 4; ++r) {
      const int grow = qrow0 + lhi*4 + r;
      #pragma unroll
      for (int n = 0; n < 4; ++n) {
        float sv = sa[n][r];
        if (diag && (kv0 + n*16 + l16 > grow)) sv = -1e9f;
        sa[n][r] = sv;
      }
      float p01 = fmaxf(sa[0][r], sa[1][r]);
      float p23 = fmaxf(sa[2][r], sa[3][r]);
      float pmx = fmaxf(p01, p23);
      pmx = fmaxf(pmx, __shfl_xor(pmx, 1));
      pmx = fmaxf(pmx, __shfl_xor(pmx, 2));
      pmx = fmaxf(pmx, __shfl_xor(pmx, 4));
      pmx = fmaxf(pmx, __shfl_xor(pmx, 8));
      pm[r] = pmx;
    }
    bool need = (pm[0] > mr[0] + 8.f) | (pm[1] > mr[1] + 8.f) |
                (pm[2] > mr[2] + 8.f) | (pm[3] > mr[3] + 8.f);
    if (__any(need)) {
      #pragma unroll
      for (int r = 0; r < 4; ++r) {
        const float mnew  = fmaxf(mr[r], pm[r]);
        const float alpha = __expf(mr[r] - mnew);
        mr[r] = mnew;
        lr[r] *= alpha;
        #pragma unroll
        for (int c = 0; c < 8; ++c) of[c][r] *= alpha;
      }
    }
    #pragma unroll
    for (int r = 0; r < 4; ++r) {
      float rsum = 0.f;
      #pragma unroll
      for (int n = 0; n < 4; ++n) {
        float pv = __expf(sa[n][r] - mr[r]);
        sa[n][r] = pv;
        rsum += pv;
      }
      rsum += __shfl_xor(rsum, 1);
      rsum += __shfl_xor(rsum, 2);
      rsum += __shfl_xor(rsum, 4);
      rsum += __shfl_xor(rsum, 8);
      lr[r] += rsum;
    }

    // ---- P -> LDS, PV ----
    #pragma unroll
    for (int r = 0; r < 4; ++r) {
      const int prow = lhi*4 + r;
      #pragma unroll
      for (int n = 0; n < 4; ++n)
        Pw[prow*64 + ((n*16 + l16) ^ ((prow & 7) << 3))] = f2bf(sa[n][r]);
    }
    __builtin_amdgcn_s_setprio(1);
    #pragma unroll
    for (int ks = 0; ks < 2; ++ks) {
      bf16x8 pf = *(const bf16x8*)(
          Pw + l16*64 + ((ks*32 + lhi*8) ^ ((l16 & 7) << 3)));
      #pragma unroll
      for (int c = 0; c < 8; ++c) {
        bf16x8 vf = *(const bf16x8*)(
            Vt + (c*16 + l16)*64 + ((ks*32 + lhi*8) ^ ((l16 & 7) << 3)));
        of[c] = __builtin_amdgcn_mfma_f32_16x16x32_bf16(pf, vf, of[c], 0, 0, 0);
      }
    }
    __builtin_amdgcn_s_setprio(0);
    __syncthreads();
  }

  #pragma unroll
  for (int r = 0; r < 4; ++r) {
    const float invl = 1.0f / lr[r];
    const long orow = (long)(qrow0 + lhi*4 + r) * QDIM + h*HD;
    #pragma unroll
    for (int c = 0; c < 8; ++c)
      O[orow + c*16 + l16] = f2bf(of[c][r] * invl);
  }
}

// ---------------------------------------------------------------------------
extern "C" void kernel_launch(void* const* d_in, const int* in_sizes, int n_in,
                              void* d_out, int out_size, void* d_ws, size_t ws_size,
                              hipStream_t stream) {
  (void)in_sizes; (void)n_in; (void)out_size; (void)ws_size;
  const float* hs  = (const float*)d_in[0];
  const int*   pos = (const int*)d_in[1];
  const float* Wq  = (const float*)d_in[2];
  const float* Wk  = (const float*)d_in[3];
  const float* Wv  = (const float*)d_in[4];
  const float* Wo  = (const float*)d_in[5];
  const float* qw  = (const float*)d_in[6];
  const float* kw  = (const float*)d_in[7];

  // Workspace layout (bf16 u16 elements), total 88 MB:
  u16* hsB = (u16*)d_ws;                          // 2048*4096
  u16* W1  = hsB + (long)S_LEN*HID;               // 4096*4096 (Wq, later Wo)
  u16* WkB = W1  + (long)QDIM*HID;                // 1024*4096
  u16* WvB = WkB + (long)KVDIM*HID;               // 1024*4096
  u16* Kb  = WvB + (long)KVDIM*HID;               // 2048*1024
  u16* VT  = Kb  + (long)S_LEN*KVDIM;             // 1024*2048 (V transposed)
  u16* AO  = VT  + (long)KVDIM*S_LEN;             // 2048*4096
  u16* Qb  = (u16*)d_out;                         // 2048*4096 (dead before final GEMM)

  f2b4<<<4096, 256, 0, stream>>>(hs, hsB, (long)S_LEN*HID/8,
                                 Wq, W1,  (long)QDIM*HID/8,
                                 Wk, WkB, (long)KVDIM*HID/8,
                                 Wv, WvB, (long)KVDIM*HID/8);

  // fused Q+K+V projection: 128x192 tile, grid 32x16 = 512 blocks (2/CU)
  gemmQ<HID><<<dim3((QDIM+2*KVDIM)/192, S_LEN/128), 512, 0, stream>>>(
      hsB, W1, Qb, Kb, VT);

  norm_rope2<<<(S_LEN*NHEADS + S_LEN*NKV)/4, 256, 0, stream>>>(
      Qb, Kb, qw, kw, pos);

  f2b<<<2048, 256, 0, stream>>>(Wo, W1, (long)HID*QDIM/8);

  // attention: 1024 blocks, XCD-chunk swizzled, balanced T per CU (r7 map)
  attn<<<dim3(NT*NHEADS), 256, 0, stream>>>(Qb, Kb, VT, AO);

  // final projection: 128x128 tile, grid 32x16 = 512 blocks (2/CU)
  gemmF<HID, QDIM><<<dim3(HID/128, S_LEN/128), 512, 0, stream>>>(
      AO, W1, (float*)d_out);
}